// Round 4
// baseline (50.482 us; speedup 1.0000x reference)
//
#include <hip/hip_runtime.h>

#define NW    4                 // waves per block
#define RPW   8                 // rows per wave
#define BROWS (NW * RPW)        // 32 rows per block
#define KC    32                // dims per chunk
#define NCH   (256 / KC)        // 8 chunks

__global__ __launch_bounds__(256, 2)
void kmad_main(const float* __restrict__ x, const float* __restrict__ coords,
               int* __restrict__ out) {
    // [buf][col][slot] with slot = d4 ^ (col & 7)  -> conflict-minimal b128 reads
    __shared__ float4 cs[2][128][8];   // 32 KB

    const int t    = threadIdx.x;
    const int lane = t & 63;
    const int wv   = __builtin_amdgcn_readfirstlane(t >> 6);
    const int rowbase = blockIdx.x * BROWS + wv * RPW;
    const float* xw = x + (size_t)rowbase * 256;   // wave-uniform -> s_load path

    // staging role: thread t covers col = t>>1, 16-float half dp = t&1
    const int scol = t >> 1;
    const int sdp  = t & 1;
    const int ssw  = scol & 7;

    // ---- prestage chunk 0 ----
    {
        const float4* g = (const float4*)(coords + (size_t)scol * 256 + sdp * 16);
        #pragma unroll
        for (int k = 0; k < 4; ++k)
            cs[0][scol][(sdp * 4 + k) ^ ssw] = g[k];
    }
    __syncthreads();

    float acc0[RPW] = {}, acc1[RPW] = {};
    float n0 = 0.f, n1 = 0.f;
    const int sw = lane & 7;   // (lane+64)&7 == lane&7

    #pragma unroll 1
    for (int ch = 0; ch < NCH; ++ch) {
        const int cur = ch & 1;

        // issue next chunk's global loads early (latency hides under FMAs)
        float4 gv[4];
        if (ch + 1 < NCH) {
            const float4* g = (const float4*)(coords + (size_t)scol * 256 + (ch + 1) * KC + sdp * 16);
            #pragma unroll
            for (int k = 0; k < 4; ++k) gv[k] = g[k];
        }

        // ---- B (coords) chunk -> registers: 16 swizzled ds_read_b128 ----
        float4 b0[8], b1[8];
        #pragma unroll
        for (int d4 = 0; d4 < 8; ++d4) {
            b0[d4] = cs[cur][lane     ][d4 ^ sw];
            b1[d4] = cs[cur][lane + 64][d4 ^ sw];
        }

        // ---- column sqnorms (accumulated across chunks) ----
        #pragma unroll
        for (int d4 = 0; d4 < 8; ++d4) {
            n0 = fmaf(b0[d4].x, b0[d4].x, n0); n0 = fmaf(b0[d4].y, b0[d4].y, n0);
            n0 = fmaf(b0[d4].z, b0[d4].z, n0); n0 = fmaf(b0[d4].w, b0[d4].w, n0);
            n1 = fmaf(b1[d4].x, b1[d4].x, n1); n1 = fmaf(b1[d4].y, b1[d4].y, n1);
            n1 = fmaf(b1[d4].z, b1[d4].z, n1); n1 = fmaf(b1[d4].w, b1[d4].w, n1);
        }

        // ---- rows: x via s_load (uniform), pure v_fmac inner loop ----
        const float* xc = xw + ch * KC;
        #pragma unroll
        for (int r = 0; r < RPW; ++r) {
            const float* xr = xc + r * 256;
            float p0 = 0.f, p1 = 0.f, q0 = 0.f, q1 = 0.f;
            #pragma unroll
            for (int d4 = 0; d4 < 8; ++d4) {
                const float x0 = xr[d4 * 4 + 0];
                const float x1 = xr[d4 * 4 + 1];
                const float x2 = xr[d4 * 4 + 2];
                const float x3 = xr[d4 * 4 + 3];
                const float4 bb0 = b0[d4], bb1 = b1[d4];
                p0 = fmaf(x0, bb0.x, p0);  q0 = fmaf(x0, bb1.x, q0);
                p1 = fmaf(x1, bb0.y, p1);  q1 = fmaf(x1, bb1.y, q1);
                p0 = fmaf(x2, bb0.z, p0);  q0 = fmaf(x2, bb1.z, q0);
                p1 = fmaf(x3, bb0.w, p1);  q1 = fmaf(x3, bb1.w, q1);
            }
            acc0[r] += p0 + p1;
            acc1[r] += q0 + q1;
        }

        // ---- write staged chunk (vmcnt wait lands after the FMA block) ----
        if (ch + 1 < NCH) {
            #pragma unroll
            for (int k = 0; k < 4; ++k)
                cs[cur ^ 1][scol][(sdp * 4 + k) ^ ssw] = gv[k];
        }
        __syncthreads();
    }

    // ---- epilogue: per-row two-smallest over 128 cols, strict compare ----
    #pragma unroll
    for (int r = 0; r < RPW; ++r) {
        const float s0 = acc0[r] + n0;    // col = lane
        const float s1 = acc1[r] + n1;    // col = lane + 64

        float m1 = fminf(s0, s1);
        float m2 = fmaxf(s0, s1);
        #pragma unroll
        for (int m = 1; m <= 32; m <<= 1) {
            const float o1 = __shfl_xor(m1, m);
            const float o2 = __shfl_xor(m2, m);
            m2 = fminf(fmaxf(m1, o1), fminf(m2, o2));
            m1 = fminf(m1, o1);
        }
        int* op = out + (size_t)(rowbase + r) * 128;
        op[lane]      = (m2 > s0) ? 1 : 0;
        op[lane + 64] = (m2 > s1) ? 1 : 0;
    }
}

extern "C" void kernel_launch(void* const* d_in, const int* in_sizes, int n_in,
                              void* d_out, int out_size, void* d_ws, size_t ws_size,
                              hipStream_t stream) {
    const float* x      = (const float*)d_in[0];   // (16384, 256) fp32
    const float* coords = (const float*)d_in[1];   // (128, 256)   fp32
    int* out = (int*)d_out;                        // (16384, 128) bool -> int32 0/1
    kmad_main<<<16384 / BROWS, NW * 64, 0, stream>>>(x, coords, out);
}

// Round 5
// 25.917 us; speedup vs baseline: 1.9479x; 1.9479x over previous
//
#include <hip/hip_runtime.h>

// s[n,k] = x[n]·coords[k] + ||coords[k]||^2 ; out[n,k] = (second_min_j s[n,j]) > s[n,k]
// Block: 64 rows x 128 cols, K-split into 4 groups of 64 dims. 512 threads, grid 256.
// LDS: cst[256][128] resident (128KB) + xs[64][64] chunk (16KB); epilogue reuses as [4][64][132].

__global__ __launch_bounds__(512, 1)
void kmad_main(const float* __restrict__ x, const float* __restrict__ coords,
               int* __restrict__ out) {
    __shared__ float lds[36864];       // 144 KB
    float* const cst = lds;            // [d][c] : 256 x 128
    float* const xs  = lds + 32768;    // [row][64] (16 swizzled 16B slots per row)
    float* const sb  = lds;            // epilogue: [4][64][132]

    const int t    = threadIdx.x;
    const int l    = t & 63;
    const int g    = t >> 7;                    // K-group 0..3
    const int wing = (t >> 6) & 1;              // wave within group
    const int r0   = (l >> 3) * 8;              // 8-row tile base
    const int c0   = ((l & 7) | (wing << 3)) * 8; // 8-col tile base
    const int m3   = l >> 3;                    // row-swizzle key (== row>>3 for r0..r0+7)
    const int row0 = blockIdx.x * 64;

    // ---- stage cst[d][c] = coords[c][d] (once) ----
    {
        const int c = t >> 2, dq = t & 3;
        const float4* src = (const float4*)(coords + (size_t)c * 256);
        #pragma unroll 4
        for (int it = 0; it < 16; ++it) {
            const int f4 = it * 4 + dq;
            float4 v = src[f4];
            float* p = cst + (size_t)(f4 * 4) * 128 + c;
            p[0] = v.x; p[128] = v.y; p[256] = v.z; p[384] = v.w;
        }
    }

    // ---- prefetch x chunk 0 into regs (reg double-buffer; xs single-buffered) ----
    const int srow = t >> 3;                    // 0..63
    const int sk   = t & 7;
    const float* xrow = x + (size_t)(row0 + srow) * 256;
    // slot sl in 0..15 holds chunk-dims [sl*4, sl*4+4) = group (sl>>2), dims (sl&3)*4..
    float4 pf0 = *(const float4*)&xrow[(sk >> 2) * 64 + (sk & 3) * 4];
    float4 pf1 = *(const float4*)&xrow[((sk + 8) >> 2) * 64 + ((sk + 8) & 3) * 4];
    const int woff0 = srow * 64 + ((sk       ^ (srow >> 3)) * 4);
    const int woff1 = srow * 64 + (((sk + 8) ^ (srow >> 3)) * 4);

    __syncthreads();   // cst staged

    float acc[8][8] = {};
    float np[8] = {};

    #pragma unroll 1
    for (int ch = 0; ch < 4; ++ch) {
        *(float4*)&xs[woff0] = pf0;
        *(float4*)&xs[woff1] = pf1;
        __syncthreads();

        if (ch < 3) {   // issue next chunk's global loads early
            pf0 = *(const float4*)&xrow[(sk >> 2) * 64 + (ch + 1) * 16 + (sk & 3) * 4];
            pf1 = *(const float4*)&xrow[((sk + 8) >> 2) * 64 + (ch + 1) * 16 + ((sk + 8) & 3) * 4];
        }

        const int dbase = g * 64 + ch * 16;
        #pragma unroll
        for (int dd4 = 0; dd4 < 4; ++dd4) {
            // A: 8 rows x 4 dims (swizzled slots -> conflict-free, 8-way broadcast)
            float4 ar[8];
            const int asl = (((g * 4 + dd4) ^ m3) * 4);
            #pragma unroll
            for (int i = 0; i < 8; ++i)
                ar[i] = *(const float4*)&xs[(r0 + i) * 64 + asl];
            // B: 4 dims x 8 cols
            float4 b0[4], b1[4];
            #pragma unroll
            for (int j = 0; j < 4; ++j) {
                const float* cp = cst + (size_t)(dbase + dd4 * 4 + j) * 128 + c0;
                b0[j] = *(const float4*)cp;
                b1[j] = *(const float4*)(cp + 4);
            }
            // col-norm partials (free from B fragments)
            #pragma unroll
            for (int j = 0; j < 4; ++j) {
                np[0] = fmaf(b0[j].x, b0[j].x, np[0]);
                np[1] = fmaf(b0[j].y, b0[j].y, np[1]);
                np[2] = fmaf(b0[j].z, b0[j].z, np[2]);
                np[3] = fmaf(b0[j].w, b0[j].w, np[3]);
                np[4] = fmaf(b1[j].x, b1[j].x, np[4]);
                np[5] = fmaf(b1[j].y, b1[j].y, np[5]);
                np[6] = fmaf(b1[j].z, b1[j].z, np[6]);
                np[7] = fmaf(b1[j].w, b1[j].w, np[7]);
            }
            // 8x8x4 FMA
            #pragma unroll
            for (int i = 0; i < 8; ++i) {
                #pragma unroll
                for (int j = 0; j < 4; ++j) {
                    const float a = (j == 0) ? ar[i].x : (j == 1) ? ar[i].y
                                  : (j == 2) ? ar[i].z : ar[i].w;
                    acc[i][0] = fmaf(a, b0[j].x, acc[i][0]);
                    acc[i][1] = fmaf(a, b0[j].y, acc[i][1]);
                    acc[i][2] = fmaf(a, b0[j].z, acc[i][2]);
                    acc[i][3] = fmaf(a, b0[j].w, acc[i][3]);
                    acc[i][4] = fmaf(a, b1[j].x, acc[i][4]);
                    acc[i][5] = fmaf(a, b1[j].y, acc[i][5]);
                    acc[i][6] = fmaf(a, b1[j].z, acc[i][6]);
                    acc[i][7] = fmaf(a, b1[j].w, acc[i][7]);
                }
            }
        }
        __syncthreads();   // xs (and, after last iter, cst) safe to overwrite
    }

    // fold norm partials into K-partials: s = sum_g (dot_g + n_g[c])
    #pragma unroll
    for (int i = 0; i < 8; ++i) {
        #pragma unroll
        for (int j = 0; j < 8; ++j) acc[i][j] += np[j];
    }

    // ---- exchange partials: sb[g][64][132] ----
    {
        float* p = sb + g * 8448;
        #pragma unroll
        for (int i = 0; i < 8; ++i) {
            float* q = p + (size_t)(r0 + i) * 132 + c0;
            *(float4*)q       = make_float4(acc[i][0], acc[i][1], acc[i][2], acc[i][3]);
            *(float4*)(q + 4) = make_float4(acc[i][4], acc[i][5], acc[i][6], acc[i][7]);
        }
    }
    __syncthreads();

    // ---- reduce 4 partials; second-min over 128; strict compare; store ----
    {
        const int rrow = t >> 3;            // 0..63
        const int cs   = (t & 7) * 16;      // 16-col slice
        const float* p = sb + (size_t)rrow * 132 + cs;
        float4 sv[4];
        #pragma unroll
        for (int u = 0; u < 4; ++u) {
            float4 a = *(const float4*)(p + u * 4);
            float4 b = *(const float4*)(p + 8448  + u * 4);
            float4 c = *(const float4*)(p + 16896 + u * 4);
            float4 d = *(const float4*)(p + 25344 + u * 4);
            sv[u].x = (a.x + b.x) + (c.x + d.x);
            sv[u].y = (a.y + b.y) + (c.y + d.y);
            sv[u].z = (a.z + b.z) + (c.z + d.z);
            sv[u].w = (a.w + b.w) + (c.w + d.w);
        }
        float m1 = fminf(sv[0].x, sv[0].y);
        float m2 = fmaxf(sv[0].x, sv[0].y);
#define UPD(v) { float hi = fmaxf(m1, (v)); m1 = fminf(m1, (v)); m2 = fminf(m2, hi); }
        UPD(sv[0].z) UPD(sv[0].w)
        UPD(sv[1].x) UPD(sv[1].y) UPD(sv[1].z) UPD(sv[1].w)
        UPD(sv[2].x) UPD(sv[2].y) UPD(sv[2].z) UPD(sv[2].w)
        UPD(sv[3].x) UPD(sv[3].y) UPD(sv[3].z) UPD(sv[3].w)
#undef UPD
        // merge across the 8 lanes sharing this row (xor 1,2,4 stay in-wave)
        #pragma unroll
        for (int m = 1; m <= 4; m <<= 1) {
            const float o1 = __shfl_xor(m1, m);
            const float o2 = __shfl_xor(m2, m);
            m2 = fminf(fmaxf(m1, o1), fminf(m2, o2));
            m1 = fminf(m1, o1);
        }
        int* op = out + (size_t)(row0 + rrow) * 128 + cs;
        #pragma unroll
        for (int u = 0; u < 4; ++u) {
            int4 o;
            o.x = (m2 > sv[u].x) ? 1 : 0;
            o.y = (m2 > sv[u].y) ? 1 : 0;
            o.z = (m2 > sv[u].z) ? 1 : 0;
            o.w = (m2 > sv[u].w) ? 1 : 0;
            *(int4*)(op + u * 4) = o;
        }
    }
}

extern "C" void kernel_launch(void* const* d_in, const int* in_sizes, int n_in,
                              void* d_out, int out_size, void* d_ws, size_t ws_size,
                              hipStream_t stream) {
    const float* x      = (const float*)d_in[0];   // (16384, 256) fp32
    const float* coords = (const float*)d_in[1];   // (128, 256)   fp32
    int* out = (int*)d_out;                        // (16384, 128) bool -> int32 0/1
    kmad_main<<<256, 512, 0, stream>>>(x, coords, out);
}